// Round 6
// baseline (209.383 us; speedup 1.0000x reference)
//
#include <hip/hip_runtime.h>

// AFM layer, MI355X gfx950.
// out[b] = sum_p attn_p * s_p,  s_p = sum_d x[i,d]x[j,d]p[d]
// R5: latency-bound per R1-R4 counters (occupancy pinned ~34% regardless of
// resources) -> attack with ILP: 2 batches per wave, two independent
// accumulation streams per iteration. Shared per-lane constants (W1^T frags,
// p-pack, b1 C-frag, w2 f16-pack); per-stream xi frags + accumulators.
// In-body chains shortened: sp = 4 parallel fdot2 trees; relu(h).w2 in packed
// f16 (cvt_pkrtz + v_pk_max + fdot2), 24 ops vs 32 and w2 in 8 VGPRs.
// Pair schedule per batch (25 MFMA iters, 780/800 slots):
//   t=1..15 : 32-rotation (nl,(nl+t)&31), all lanes valid (prod symmetric).
//   t=16    : half-rotation, lanes nl<16.
//   t=17..24: j=32+t-17 uniform row, i=nl<32<=j.
//   cleanup : 8-triangle of fields 32..39 (28 pairs, closed-form unrank).
// LDS: stride-64 rows + XOR swizzle of 16B granules (blk^=row&7): single
// ds_read_b128 per frag; residual ~2.6 conflict-cyc/b128 is pigeonhole-
// structural (1 KiB/wave-read > 2 passes of 32 banks) — not actionable.
// __launch_bounds__(256,4): (256,8) strangles allocator -> 2.1 GB spill (R3).

typedef _Float16 f16;
typedef f16 f16x2 __attribute__((ext_vector_type(2)));
typedef f16 f16x8 __attribute__((ext_vector_type(8)));
typedef float fx16 __attribute__((ext_vector_type(16)));

#define NF 40
#define NB 8192

union V8 { f16x8 v8; f16x2 v2[4]; };

__global__ __launch_bounds__(256, 4) void afm_kernel(
    const float* __restrict__ x,   // [8192,40,64]
    const float* __restrict__ W1,  // [64,32]
    const float* __restrict__ b1,  // [32]
    const float* __restrict__ w2,  // [32]
    const float* __restrict__ p,   // [64]
    float* __restrict__ out)       // [8192]
{
    __shared__ f16 xh[8][NF * 64];   // 8 batches x 40 rows x 64 f16 = 40,960 B

    const int tid  = threadIdx.x;
    const int wid  = tid >> 6;
    const int lane = tid & 63;
    const int b0   = blockIdx.x * 8 + wid * 2;   // this wave: batches b0, b0+1

    f16* Xs0 = &xh[wid * 2][0];
    f16* Xs1 = &xh[wid * 2 + 1][0];

    // ---- stage 2 batches (5120 contiguous floats) -> LDS f16, swizzled ----
    // 640 granules of 8 f16; granule gi of row r lands at blk = (gi&7)^(r&7).
    const float4* xb = (const float4*)(x + (size_t)b0 * (NF * 64));
#pragma unroll
    for (int t = 0; t < 10; ++t) {
        int g = t * 64 + lane;                 // 0..639
        float4 v0 = xb[g * 2];
        float4 v1 = xb[g * 2 + 1];
        f16x8 h = { (f16)v0.x, (f16)v0.y, (f16)v0.z, (f16)v0.w,
                    (f16)v1.x, (f16)v1.y, (f16)v1.z, (f16)v1.w };
        int bsel = (g >= 320);
        int gi = g - (bsel ? 320 : 0);         // 0..319 within batch
        int row = gi >> 3, gg = gi & 7;
        int blk = gg ^ (row & 7);
        *(f16x8*)((bsel ? Xs1 : Xs0) + (row << 6) + blk * 8) = h;
    }
    __syncthreads();

    const int nl = lane & 31;   // MFMA column / field index base
    const int hh = lane >> 5;   // wave half -> k sub-block + a-row group
    const int h8 = hh * 8;

    // ---- A-frags: W1^T, A[m=a][k=h8+j], d = kt*16 + h8 + j ----
    f16x8 w1f[4];
#pragma unroll
    for (int kt = 0; kt < 4; ++kt)
#pragma unroll
        for (int j = 0; j < 8; ++j)
            w1f[kt][j] = (f16)W1[(kt * 16 + h8 + j) * 32 + nl];

    // ---- p packed to match prod-frag element order (for fdot2) ----
    f16x2 pp[16];
#pragma unroll
    for (int kt = 0; kt < 4; ++kt)
#pragma unroll
        for (int m = 0; m < 4; ++m) {
            f16x2 t2 = { (f16)p[kt * 16 + h8 + 2 * m], (f16)p[kt * 16 + h8 + 2 * m + 1] };
            pp[kt * 4 + m] = t2;
        }

    // ---- b1 as persistent C-frag; w2 packed f16 pairs (consecutive a) ----
    fx16 b1C;
    f16x2 w2h[8];
#pragma unroll
    for (int r = 0; r < 16; ++r) {
        int a = (r & 3) + 8 * (r >> 2) + 4 * hh;
        b1C[r] = b1[a];
    }
#pragma unroll
    for (int m = 0; m < 8; ++m) {
        int r = 2 * m;
        int a = (r & 3) + 8 * (r >> 2) + 4 * hh;
        f16x2 t2 = { (f16)w2[a], (f16)w2[a + 1] };
        w2h[m] = t2;
    }

    // ---- xi frags for row nl, both streams ----
    f16x8 xif0[4], xif1[4];
    {
        int rb = nl & 7;
        const f16* r0 = Xs0 + (nl << 6);
        const f16* r1 = Xs1 + (nl << 6);
#pragma unroll
        for (int kt = 0; kt < 4; ++kt) {
            int blk = (kt * 2 + hh) ^ rb;
            xif0[kt] = *(const f16x8*)(r0 + blk * 8);
            xif1[kt] = *(const f16x8*)(r1 + blk * 8);
        }
    }

    float aW0 = 0.f, aS0 = 0.f, aW1 = 0.f, aS1 = 0.f;

    auto body = [&](const f16* Xs, const f16x8* xi, int jrow,
                    float& aW, float& aS, bool valid) {
        int rb = jrow & 7;
        const f16* rowp = Xs + (jrow << 6);
        V8 pr[4];
#pragma unroll
        for (int kt = 0; kt < 4; ++kt) {
            int blk = (kt * 2 + hh) ^ rb;
            f16x8 xj = *(const f16x8*)(rowp + blk * 8);   // ds_read_b128
            pr[kt].v8 = xi[kt] * xj;                       // v_pk_mul_f16 x4
        }
        // h = W1^T prod + b1 : chain C from persistent b1 frag
        fx16 C = __builtin_amdgcn_mfma_f32_32x32x16_f16(w1f[0], pr[0].v8, b1C, 0, 0, 0);
        C = __builtin_amdgcn_mfma_f32_32x32x16_f16(w1f[1], pr[1].v8, C, 0, 0, 0);
        C = __builtin_amdgcn_mfma_f32_32x32x16_f16(w1f[2], pr[2].v8, C, 0, 0, 0);
        C = __builtin_amdgcn_mfma_f32_32x32x16_f16(w1f[3], pr[3].v8, C, 0, 0, 0);
        // s_p partial: 4 parallel fdot2 trees (chain depth 4, not 16)
        float s0 = 0.f, s1 = 0.f, s2 = 0.f, s3 = 0.f;
#pragma unroll
        for (int m = 0; m < 4; ++m) {
            s0 = __builtin_amdgcn_fdot2(pr[0].v2[m], pp[m],      s0, false);
            s1 = __builtin_amdgcn_fdot2(pr[1].v2[m], pp[4 + m],  s1, false);
            s2 = __builtin_amdgcn_fdot2(pr[2].v2[m], pp[8 + m],  s2, false);
            s3 = __builtin_amdgcn_fdot2(pr[3].v2[m], pp[12 + m], s3, false);
        }
        float sp = (s0 + s1) + (s2 + s3);
        // logit partial: relu(h).w2 in packed f16, 2 parallel trees
        const f16x2 z2 = { (f16)0.f, (f16)0.f };
        float l0 = 0.f, l1 = 0.f;
#pragma unroll
        for (int m = 0; m < 8; ++m) {
            f16x2 hm = __builtin_bit_cast(f16x2,
                __builtin_amdgcn_cvt_pkrtz(C[2 * m], C[2 * m + 1]));
            hm = __builtin_elementwise_max(hm, z2);        // v_pk_max_f16
            if (m & 1) l1 = __builtin_amdgcn_fdot2(hm, w2h[m], l1, false);
            else       l0 = __builtin_amdgcn_fdot2(hm, w2h[m], l0, false);
        }
        float l = l0 + l1;
        l  += __shfl_xor(l, 32);    // combine a-halves
        sp += __shfl_xor(sp, 32);   // combine k-halves
        float w = __expf(l);        // max-free softmax (|l| small)
        if (!valid) w = 0.f;
        aW += w;
        aS = fmaf(w, sp, aS);
    };

    // Phases A+B fused: t=1..16 rotation, t=17..24 uniform rows 32..39
    for (int t = 1; t <= 24; ++t) {
        int jrow = (t <= 16) ? ((nl + t) & 31) : (t + 15);
        bool valid = (t != 16) || (nl < 16);
        body(Xs0, xif0, jrow, aW0, aS0, valid);
        body(Xs1, xif1, jrow, aW1, aS1, valid);
    }

    // Phase C: 28 pairs among fields 32..39 (lanes nl<28)
    {
        int q = nl < 28 ? nl : 27;
        float disc = 225.0f - 8.0f * (float)q;
        int ii = (int)((15.0f - sqrtf(disc)) * 0.5f);
        if (ii * (15 - ii) / 2 > q) --ii;                 // sqrt 1-ulp fixups
        if ((ii + 1) * (14 - ii) / 2 <= q) ++ii;
        int jj = q - ii * (15 - ii) / 2 + ii + 1;
        int iC = 32 + ii, jC = 32 + jj;                   // pair (iC,jC), iC<jC
        bool vC = nl < 28;
        int rb = iC & 7;
        f16x8 xi2[4];
        const f16* r0 = Xs0 + (iC << 6);
#pragma unroll
        for (int kt = 0; kt < 4; ++kt)
            xi2[kt] = *(const f16x8*)(r0 + (((kt * 2 + hh) ^ rb)) * 8);
        body(Xs0, xi2, jC, aW0, aS0, vC);
        const f16* r1 = Xs1 + (iC << 6);
#pragma unroll
        for (int kt = 0; kt < 4; ++kt)
            xi2[kt] = *(const f16x8*)(r1 + (((kt * 2 + hh) ^ rb)) * 8);
        body(Xs1, xi2, jC, aW1, aS1, vC);
    }

    // reduce across the 32 columns (halves already identical)
#pragma unroll
    for (int m = 16; m >= 1; m >>= 1) {
        aW0 += __shfl_xor(aW0, m);
        aS0 += __shfl_xor(aS0, m);
        aW1 += __shfl_xor(aW1, m);
        aS1 += __shfl_xor(aS1, m);
    }
    if (lane == 0) {
        out[b0]     = aS0 / aW0;
        out[b0 + 1] = aS1 / aW1;
    }
}

extern "C" void kernel_launch(void* const* d_in, const int* in_sizes, int n_in,
                              void* d_out, int out_size, void* d_ws, size_t ws_size,
                              hipStream_t stream) {
    const float* x  = (const float*)d_in[0];
    const float* W1 = (const float*)d_in[1];
    const float* b1 = (const float*)d_in[2];
    const float* w2 = (const float*)d_in[3];
    const float* p  = (const float*)d_in[4];
    float* out = (float*)d_out;
    dim3 grid(NB / 8), block(256);
    hipLaunchKernelGGL(afm_kernel, grid, block, 0, stream, x, W1, b1, w2, p, out);
}

// Round 7
// 151.962 us; speedup vs baseline: 1.3779x; 1.3779x over previous
//
#include <hip/hip_runtime.h>

// AFM layer, MI355X gfx950.
// out[b] = sum_p attn_p * s_p,  s_p = sum_d x[i,d]x[j,d]p[d]
// R7: latency-bound -> raise TLP, not per-wave registers (R6: 2-stream ILP
// spilled 72 MB scratch, 1.8x regression). TWO waves per batch share one LDS
// X-copy and split the 25 bodies 12/13; partial (accW,accWS) combined via a
// tiny LDS reduce. Waves double: 16384 = 64/CU = 2 generations -> backfill.
// LDS: R2's padded stride-76 rows, b64 accesses — MEASURED 0 bank conflicts
// (R4's XOR-swizzle b128 carried 2.2M conflict-cyc ~= its 3.5us deficit).
// Body: prod in-register (v_pk_mul), 4 chained MFMA 32x32x16_f16 with b1 as
// persistent C-frag; sp = 4 parallel fdot2 trees; relu(h).w2 packed f16
// (cvt_pkrtz + pk_max + fdot2) with log2e folded into w2 -> exp2 direct.
// Pair schedule per batch (25 bodies, 780/800 slots):
//   t=1..15 : 32-rotation (nl,(nl+t)&31) all-valid (prod symmetric);
//   t=16    : half-rotation, nl<16;  t=17..24: uniform rows 32..39;
//   cleanup : 8-triangle of fields 32..39 (28 pairs, closed-form unrank).
// Role 0: t=1..12. Role 1: t=13..24 + cleanup.
// __launch_bounds__(256,4): (256,8) strangles allocator -> spill (R3).

typedef _Float16 f16;
typedef f16 f16x2 __attribute__((ext_vector_type(2)));
typedef f16 f16x4 __attribute__((ext_vector_type(4)));
typedef f16 f16x8 __attribute__((ext_vector_type(8)));
typedef float fx16 __attribute__((ext_vector_type(16)));

#define NF 40
#define NB 8192
#define STR 76   // f16 elements per LDS row (152 B) — conflict-free (R2)

union V8 { f16x8 v8; f16x4 v4[2]; f16x2 v2[4]; };

__global__ __launch_bounds__(256, 4) void afm_kernel(
    const float* __restrict__ x,   // [8192,40,64]
    const float* __restrict__ W1,  // [64,32]
    const float* __restrict__ b1,  // [32]
    const float* __restrict__ w2,  // [32]
    const float* __restrict__ p,   // [64]
    float* __restrict__ out)       // [8192]
{
    __shared__ f16 xh[2][NF * STR];     // 2 batches x 40 x 76 f16 = 12,160 B
    __shared__ float red[2][2][2];      // [batch][role][aW,aS]

    const int tid  = threadIdx.x;
    const int wid  = tid >> 6;
    const int lane = tid & 63;
    const int bl   = wid >> 1;          // batch-local 0/1
    const int role = wid & 1;           // 0: t=1..12, 1: t=13..24 + cleanup
    const int b0   = blockIdx.x * 2;

    f16* Xs = &xh[bl][0];

    // ---- stage 2 batches (5120 floats) -> LDS f16, stride-76 rows ----
    const float4* xb = (const float4*)(x + (size_t)b0 * (NF * 64));
#pragma unroll
    for (int t = 0; t < 3; ++t) {
        int g = t * 256 + tid;                 // granule 0..639 (8 f16 each)
        if (g < 640) {
            float4 v0 = xb[g * 2];
            float4 v1 = xb[g * 2 + 1];
            f16x4 lo = { (f16)v0.x, (f16)v0.y, (f16)v0.z, (f16)v0.w };
            f16x4 hi = { (f16)v1.x, (f16)v1.y, (f16)v1.z, (f16)v1.w };
            int bsel = (g >= 320);
            int gi = g - (bsel ? 320 : 0);
            int row = gi >> 3, gg = gi & 7;
            f16* dst = &xh[bsel][0] + row * STR + gg * 8;
            *(f16x4*)dst = lo;                 // 8B-aligned b64 writes
            *(f16x4*)(dst + 4) = hi;
        }
    }
    __syncthreads();

    const int nl = lane & 31;   // MFMA column / field index base
    const int hh = lane >> 5;   // wave half -> k sub-block + a-row group
    const int h8 = hh * 8;

    // ---- A-frags: W1^T, A[m=a][k=h8+j], d = kt*16 + h8 + j ----
    f16x8 w1f[4];
#pragma unroll
    for (int kt = 0; kt < 4; ++kt)
#pragma unroll
        for (int j = 0; j < 8; ++j)
            w1f[kt][j] = (f16)W1[(kt * 16 + h8 + j) * 32 + nl];

    // ---- p packed to match prod-frag element order (for fdot2) ----
    f16x2 pp[16];
#pragma unroll
    for (int kt = 0; kt < 4; ++kt)
#pragma unroll
        for (int m = 0; m < 4; ++m) {
            f16x2 t2 = { (f16)p[kt * 16 + h8 + 2 * m], (f16)p[kt * 16 + h8 + 2 * m + 1] };
            pp[kt * 4 + m] = t2;
        }

    // ---- b1 as persistent C-frag; w2*log2e packed f16 (exp2 direct) ----
    fx16 b1C;
    f16x2 w2h[8];
#pragma unroll
    for (int r = 0; r < 16; ++r) {
        int a = (r & 3) + 8 * (r >> 2) + 4 * hh;
        b1C[r] = b1[a];
    }
#pragma unroll
    for (int m = 0; m < 8; ++m) {
        int r = 2 * m;
        int a = (r & 3) + 8 * (r >> 2) + 4 * hh;
        f16x2 t2 = { (f16)(w2[a] * 1.44269504f), (f16)(w2[a + 1] * 1.44269504f) };
        w2h[m] = t2;
    }

    // ---- xi frags for row nl ----
    f16x4 xif[8];
    {
        const f16* src = Xs + nl * STR + h8;
#pragma unroll
        for (int kt = 0; kt < 4; ++kt) {
            xif[2 * kt]     = *(const f16x4*)(src + kt * 16);
            xif[2 * kt + 1] = *(const f16x4*)(src + kt * 16 + 4);
        }
    }

    float accW = 0.f, accWS = 0.f;

    auto body = [&](const f16x4* xi, int jrow, bool valid) {
        const f16* base = Xs + jrow * STR + h8;
        V8 pr[4];
#pragma unroll
        for (int kt = 0; kt < 4; ++kt) {
            f16x4 a0 = *(const f16x4*)(base + kt * 16);       // ds_read_b64
            f16x4 a1 = *(const f16x4*)(base + kt * 16 + 4);
            pr[kt].v4[0] = xi[2 * kt] * a0;                    // v_pk_mul_f16
            pr[kt].v4[1] = xi[2 * kt + 1] * a1;
        }
        // h = W1^T prod + b1 : chain C from persistent b1 frag
        fx16 C = __builtin_amdgcn_mfma_f32_32x32x16_f16(w1f[0], pr[0].v8, b1C, 0, 0, 0);
        C = __builtin_amdgcn_mfma_f32_32x32x16_f16(w1f[1], pr[1].v8, C, 0, 0, 0);
        C = __builtin_amdgcn_mfma_f32_32x32x16_f16(w1f[2], pr[2].v8, C, 0, 0, 0);
        C = __builtin_amdgcn_mfma_f32_32x32x16_f16(w1f[3], pr[3].v8, C, 0, 0, 0);
        // s_p partial: 4 parallel fdot2 trees (chain depth 4)
        float s0 = 0.f, s1 = 0.f, s2 = 0.f, s3 = 0.f;
#pragma unroll
        for (int m = 0; m < 4; ++m) {
            s0 = __builtin_amdgcn_fdot2(pr[0].v2[m], pp[m],      s0, false);
            s1 = __builtin_amdgcn_fdot2(pr[1].v2[m], pp[4 + m],  s1, false);
            s2 = __builtin_amdgcn_fdot2(pr[2].v2[m], pp[8 + m],  s2, false);
            s3 = __builtin_amdgcn_fdot2(pr[3].v2[m], pp[12 + m], s3, false);
        }
        float sp = (s0 + s1) + (s2 + s3);
        // logit partial: relu(h).(w2*log2e) in packed f16, 2 parallel trees
        const f16x2 z2 = { (f16)0.f, (f16)0.f };
        float l0 = 0.f, l1 = 0.f;
#pragma unroll
        for (int m = 0; m < 8; ++m) {
            f16x2 hm = __builtin_bit_cast(f16x2,
                __builtin_amdgcn_cvt_pkrtz(C[2 * m], C[2 * m + 1]));
            hm = __builtin_elementwise_max(hm, z2);            // v_pk_max_f16
            if (m & 1) l1 = __builtin_amdgcn_fdot2(hm, w2h[m], l1, false);
            else       l0 = __builtin_amdgcn_fdot2(hm, w2h[m], l0, false);
        }
        float l = l0 + l1;
        l  += __shfl_xor(l, 32);    // combine a-halves
        sp += __shfl_xor(sp, 32);   // combine k-halves
        float w = __builtin_amdgcn_exp2f(l);   // max-free softmax (|l| small)
        if (!valid) w = 0.f;
        accW += w;
        accWS = fmaf(w, sp, accWS);
    };

    // 12 (role 0) or 12+cleanup (role 1) bodies
    const int tb = 1 + role * 12;
    for (int t = tb; t < tb + 12; ++t) {
        int jrow = (t <= 16) ? ((nl + t) & 31) : (t + 15);
        bool valid = (t != 16) || (nl < 16);
        body(xif, jrow, valid);
    }
    if (role) {   // cleanup: 28 pairs among fields 32..39 (lanes nl<28)
        int q = nl < 28 ? nl : 27;
        float disc = 225.0f - 8.0f * (float)q;
        int ii = (int)((15.0f - sqrtf(disc)) * 0.5f);
        if (ii * (15 - ii) / 2 > q) --ii;                 // sqrt 1-ulp fixups
        if ((ii + 1) * (14 - ii) / 2 <= q) ++ii;
        int jj = q - ii * (15 - ii) / 2 + ii + 1;
        int iC = 32 + ii, jC = 32 + jj;                   // pair (iC,jC), iC<jC
        f16x4 xi2[8];
        const f16* src = Xs + iC * STR + h8;
#pragma unroll
        for (int kt = 0; kt < 4; ++kt) {
            xi2[2 * kt]     = *(const f16x4*)(src + kt * 16);
            xi2[2 * kt + 1] = *(const f16x4*)(src + kt * 16 + 4);
        }
        body(xi2, jC, nl < 28);
    }

    // reduce across the 32 columns (halves already identical)
#pragma unroll
    for (int m = 16; m >= 1; m >>= 1) {
        accW  += __shfl_xor(accW, m);
        accWS += __shfl_xor(accWS, m);
    }
    if (lane == 0) {
        red[bl][role][0] = accW;
        red[bl][role][1] = accWS;
    }
    __syncthreads();
    if (tid < 2) {
        float W = red[tid][0][0] + red[tid][1][0];
        float S = red[tid][0][1] + red[tid][1][1];
        out[b0 + tid] = S / W;
    }
}

extern "C" void kernel_launch(void* const* d_in, const int* in_sizes, int n_in,
                              void* d_out, int out_size, void* d_ws, size_t ws_size,
                              hipStream_t stream) {
    const float* x  = (const float*)d_in[0];
    const float* W1 = (const float*)d_in[1];
    const float* b1 = (const float*)d_in[2];
    const float* w2 = (const float*)d_in[3];
    const float* p  = (const float*)d_in[4];
    float* out = (float*)d_out;
    dim3 grid(NB / 2), block(256);
    hipLaunchKernelGGL(afm_kernel, grid, block, 0, stream, x, W1, b1, w2, p, out);
}